// Round 1
// baseline (300.344 us; speedup 1.0000x reference)
//
#include <hip/hip_runtime.h>

#define H_   256
#define W_   256
#define HW_  65536
#define C_   256
#define MID  16
#define B_   2

// ---------------------------------------------------------------------------
// K0: one tiny block. Computes the 4 normalized anisotropic Gaussian 7x7
// kernels into ws, and transposes reduce_w [m][c] -> [c][m] so K1 can use
// consecutive scalar loads (s_load_dwordx16).
// ---------------------------------------------------------------------------
__global__ __launch_bounds__(256) void k0_prep(const float* __restrict__ rw,
                                               float* __restrict__ base_out,
                                               float* __restrict__ rwt) {
    __shared__ float s_k[4][49];
    __shared__ float s_inv[4];
    int t = threadIdx.x;
    if (t < 196) {
        int k = t / 49, p = t % 49;
        int i = p / 7, j = p % 7;
        float xx = (float)(i - 3), yy = (float)(j - 3);
        const float cs[4] = {1.0f, 0.70710678118654752f, 0.0f, -0.70710678118654752f};
        const float sn[4] = {0.0f, 0.70710678118654752f, 1.0f, 0.70710678118654752f};
        float c = cs[k], s = sn[k];
        float xr = xx * c + yy * s;
        float yr = -xx * s + yy * c;
        // sigma1=2.5 -> 1/(2*6.25)=0.08 ; sigma2=1.0 -> 1/2 = 0.5
        float v = expf(-(xr * xr * 0.08f + yr * yr * 0.5f));
        s_k[k][p] = v;
    }
    __syncthreads();
    if (t < 4) {
        float s = 0.f;
        for (int p = 0; p < 49; ++p) s += s_k[t][p];
        s_inv[t] = 1.0f / s;
    }
    __syncthreads();
    if (t < 196) base_out[t] = s_k[t / 49][t % 49] * s_inv[t / 49];
    // transpose reduce_w: rwt[c*16+m] = rw[m*256+c]
    for (int idx = t; idx < MID * C_; idx += 256) {
        int c = idx >> 4, m = idx & 15;
        rwt[idx] = rw[m * C_ + c];
    }
}

// ---------------------------------------------------------------------------
// K1: x_low[b,m,h,w] = sum_c x[b,c,h,w] * reduce_w[m,c]
// 2 pixels per thread (float2 loads, 8B/lane coalesced). 256 blocks x 256 thr.
// Weights read via uniform scalar loads (consecutive 16 floats per c).
// ---------------------------------------------------------------------------
__global__ __launch_bounds__(256) void k1_reduce(const float* __restrict__ x,
                                                 const float* __restrict__ rwt,
                                                 float* __restrict__ xlow) {
    int g = blockIdx.x * 256 + threadIdx.x;
    int p0 = g * 2;
    int b = p0 >> 16;          // HW_ = 65536
    int pix = p0 & (HW_ - 1);
    const float2* xp = (const float2*)(x + (size_t)b * C_ * HW_ + pix);
    float2 acc[MID];
#pragma unroll
    for (int m = 0; m < MID; ++m) acc[m] = make_float2(0.f, 0.f);
#pragma unroll 4
    for (int c = 0; c < C_; ++c) {
        float2 v = xp[c * (HW_ / 2)];
#pragma unroll
        for (int m = 0; m < MID; ++m) {
            float w = rwt[c * MID + m];   // uniform -> scalar load
            acc[m].x = fmaf(w, v.x, acc[m].x);
            acc[m].y = fmaf(w, v.y, acc[m].y);
        }
    }
    float* ob = xlow + (size_t)b * MID * HW_ + pix;
#pragma unroll
    for (int m = 0; m < MID; ++m) {
        *(float2*)(ob + m * HW_) = acc[m];
    }
}

// ---------------------------------------------------------------------------
// K2: per-pixel: angle MLP -> softmax weights -> blend base kernels ->
// 7x7 reflect-padded conv over 16 channels -> 16->256 expand -> out.
// One block per (b,h) row; thread = w. 512 blocks x 256 thr.
// ---------------------------------------------------------------------------
__global__ __launch_bounds__(256) void k2_fused(const float* __restrict__ xlow,
                                                const float* __restrict__ base,
                                                const float* __restrict__ angle,
                                                const float* __restrict__ w1,
                                                const float* __restrict__ b1,
                                                const float* __restrict__ w2,
                                                const float* __restrict__ b2,
                                                const float* __restrict__ ew,
                                                float* __restrict__ out) {
    int bh = blockIdx.x;
    int b = bh >> 8, h = bh & 255;
    int w = threadIdx.x;

    // ---- MLP + softmax -> wk[4] ----
    float a2 = 2.0f * angle[(size_t)b * HW_ + h * W_ + w];
    float f0 = __sinf(a2), f1 = __cosf(a2);
    float hb[8];
#pragma unroll
    for (int j = 0; j < 8; ++j) {
        hb[j] = fmaxf(fmaf(w1[j * 2], f0, fmaf(w1[j * 2 + 1], f1, b1[j])), 0.f);
    }
    float lg[4];
#pragma unroll
    for (int k = 0; k < 4; ++k) {
        float s = b2[k];
#pragma unroll
        for (int j = 0; j < 8; ++j) s = fmaf(w2[k * 8 + j], hb[j], s);
        lg[k] = s;
    }
    float mx = fmaxf(fmaxf(lg[0], lg[1]), fmaxf(lg[2], lg[3]));
    float wk[4];
    float ssum = 0.f;
#pragma unroll
    for (int k = 0; k < 4; ++k) { wk[k] = __expf(lg[k] - mx); ssum += wk[k]; }
    float inv = 1.0f / ssum;
#pragma unroll
    for (int k = 0; k < 4; ++k) wk[k] *= inv;

    // ---- 7x7 directional conv on 16 channels (reflect padding) ----
    float acc[MID];
#pragma unroll
    for (int m = 0; m < MID; ++m) acc[m] = 0.f;
    const float* xb = xlow + (size_t)b * MID * HW_;
    int cc[7];
#pragma unroll
    for (int dx = 0; dx < 7; ++dx) {
        int c0 = w + dx - 3;
        cc[dx] = c0 < 0 ? -c0 : (c0 > 255 ? 510 - c0 : c0);
    }
    for (int dy = 0; dy < 7; ++dy) {
        int hy = h + dy - 3;
        hy = hy < 0 ? -hy : (hy > 255 ? 510 - hy : hy);
        float e[7];
#pragma unroll
        for (int dx = 0; dx < 7; ++dx) {
            int tp = dy * 7 + dx;
            e[dx] = fmaf(wk[0], base[tp],
                    fmaf(wk[1], base[49 + tp],
                    fmaf(wk[2], base[98 + tp], wk[3] * base[147 + tp])));
        }
        const float* rowb = xb + hy * W_;
#pragma unroll
        for (int m = 0; m < MID; ++m) {
            const float* row = rowb + (size_t)m * HW_;
            float s = acc[m];
#pragma unroll
            for (int dx = 0; dx < 7; ++dx) s = fmaf(e[dx], row[cc[dx]], s);
            acc[m] = s;
        }
    }

    // ---- expand 16 -> 256 and store ----
    float* ob = out + (size_t)b * C_ * HW_ + h * W_ + w;
#pragma unroll 4
    for (int c = 0; c < C_; ++c) {
        float s = 0.f;
#pragma unroll
        for (int m = 0; m < MID; ++m) s = fmaf(ew[c * MID + m], acc[m], s);
        __builtin_nontemporal_store(s, ob + (size_t)c * HW_);
    }
}

// ---------------------------------------------------------------------------
extern "C" void kernel_launch(void* const* d_in, const int* in_sizes, int n_in,
                              void* d_out, int out_size, void* d_ws, size_t ws_size,
                              hipStream_t stream) {
    const float* x     = (const float*)d_in[0];
    const float* angle = (const float*)d_in[1];
    const float* rw    = (const float*)d_in[2];
    const float* ew    = (const float*)d_in[3];
    const float* w1    = (const float*)d_in[4];
    const float* b1    = (const float*)d_in[5];
    const float* w2    = (const float*)d_in[6];
    const float* b2    = (const float*)d_in[7];
    float* out = (float*)d_out;

    float* wsf  = (float*)d_ws;
    float* base = wsf;            // 196 floats
    float* rwt  = wsf + 256;      // 4096 floats
    float* xlow = wsf + 8192;     // 2*16*65536 floats = 8.4 MB

    hipLaunchKernelGGL(k0_prep,  dim3(1),   dim3(256), 0, stream, rw, base, rwt);
    hipLaunchKernelGGL(k1_reduce, dim3(256), dim3(256), 0, stream, x, rwt, xlow);
    hipLaunchKernelGGL(k2_fused, dim3(512), dim3(256), 0, stream,
                       xlow, base, angle, w1, b1, w2, b2, ew, out);
}

// Round 2
// 295.750 us; speedup vs baseline: 1.0155x; 1.0155x over previous
//
#include <hip/hip_runtime.h>

#define H_   256
#define W_   256
#define HW_  65536
#define C_   256
#define MID  16
#define B_   2

// ---------------------------------------------------------------------------
// K0: one tiny block. Computes the 4 normalized anisotropic Gaussian 7x7
// kernels and transposes reduce_w [m][c] -> [c][m] (64B-aligned rows so kA's
// uniform weight reads become s_load_dwordx16).
// ---------------------------------------------------------------------------
__global__ __launch_bounds__(256) void k0_prep(const float* __restrict__ rw,
                                               float* __restrict__ base_out,
                                               float* __restrict__ rwt) {
    __shared__ float s_k[4][49];
    __shared__ float s_inv[4];
    int t = threadIdx.x;
    if (t < 196) {
        int k = t / 49, p = t % 49;
        int i = p / 7, j = p % 7;
        float xx = (float)(i - 3), yy = (float)(j - 3);
        const float cs[4] = {1.0f, 0.70710678118654752f, 0.0f, -0.70710678118654752f};
        const float sn[4] = {0.0f, 0.70710678118654752f, 1.0f, 0.70710678118654752f};
        float c = cs[k], s = sn[k];
        float xr = xx * c + yy * s;
        float yr = -xx * s + yy * c;
        float v = expf(-(xr * xr * 0.08f + yr * yr * 0.5f));
        s_k[k][p] = v;
    }
    __syncthreads();
    if (t < 4) {
        float s = 0.f;
        for (int p = 0; p < 49; ++p) s += s_k[t][p];
        s_inv[t] = 1.0f / s;
    }
    __syncthreads();
    if (t < 196) base_out[t] = s_k[t / 49][t % 49] * s_inv[t / 49];
    for (int idx = t; idx < MID * C_; idx += 256) {
        int c = idx >> 4, m = idx & 15;
        rwt[idx] = rw[m * C_ + c];
    }
}

// ---------------------------------------------------------------------------
// kA: x_low (px-major) [b][h*W+w][16] = sum_c x[b,c,h,w] * rwt[c][m]
// 512 blocks (b,h row) x 256 thr (w). 16-deep load pipeline, nontemporal x.
// ---------------------------------------------------------------------------
__global__ __launch_bounds__(256) void kA_reduce(const float* __restrict__ x,
                                                 const float* __restrict__ rwt,
                                                 float* __restrict__ xlow) {
    int bh = blockIdx.x;
    int b = bh >> 8, h = bh & 255;
    int w = threadIdx.x;
    const float* xp = x + (size_t)b * C_ * HW_ + h * W_ + w;
    float acc[MID];
#pragma unroll
    for (int m = 0; m < MID; ++m) acc[m] = 0.f;
    for (int cb = 0; cb < C_; cb += 16) {
        float xv[16];
#pragma unroll
        for (int i = 0; i < 16; ++i)
            xv[i] = __builtin_nontemporal_load(xp + (size_t)(cb + i) * HW_);
#pragma unroll
        for (int i = 0; i < 16; ++i) {
#pragma unroll
            for (int m = 0; m < MID; ++m)
                acc[m] = fmaf(rwt[(cb + i) * MID + m], xv[i], acc[m]);
        }
    }
    float4* op = (float4*)(xlow + ((size_t)b * HW_ + h * W_ + w) * MID);
    op[0] = make_float4(acc[0], acc[1], acc[2], acc[3]);
    op[1] = make_float4(acc[4], acc[5], acc[6], acc[7]);
    op[2] = make_float4(acc[8], acc[9], acc[10], acc[11]);
    op[3] = make_float4(acc[12], acc[13], acc[14], acc[15]);
}

// ---------------------------------------------------------------------------
// kB: per-pixel MLP->softmax->blended 7x7 kernel, conv over 8 channels
// (m-half per block). px-major in/out -> all loads are dwordx4.
// 1024 blocks = b(2) x h(256) x mh(2); 256 thr = w.
// ---------------------------------------------------------------------------
__global__ __launch_bounds__(256) void kB_conv(const float* __restrict__ xlow,
                                               const float* __restrict__ base,
                                               const float* __restrict__ angle,
                                               const float* __restrict__ w1,
                                               const float* __restrict__ b1,
                                               const float* __restrict__ w2,
                                               const float* __restrict__ b2,
                                               float* __restrict__ olow) {
    int bid = blockIdx.x;
    int mh = bid & 1;
    int h = (bid >> 1) & 255;
    int b = bid >> 9;
    int w = threadIdx.x;

    // ---- MLP + softmax -> wk[4] ----
    float a2 = 2.0f * angle[(size_t)b * HW_ + h * W_ + w];
    float f0 = __sinf(a2), f1 = __cosf(a2);
    float hb[8];
#pragma unroll
    for (int j = 0; j < 8; ++j)
        hb[j] = fmaxf(fmaf(w1[j * 2], f0, fmaf(w1[j * 2 + 1], f1, b1[j])), 0.f);
    float lg[4];
#pragma unroll
    for (int k = 0; k < 4; ++k) {
        float s = b2[k];
#pragma unroll
        for (int j = 0; j < 8; ++j) s = fmaf(w2[k * 8 + j], hb[j], s);
        lg[k] = s;
    }
    float mx = fmaxf(fmaxf(lg[0], lg[1]), fmaxf(lg[2], lg[3]));
    float wk[4];
    float ssum = 0.f;
#pragma unroll
    for (int k = 0; k < 4; ++k) { wk[k] = __expf(lg[k] - mx); ssum += wk[k]; }
    float inv = 1.0f / ssum;
#pragma unroll
    for (int k = 0; k < 4; ++k) wk[k] *= inv;

    // ---- conv: 8 channels (this m-half), 7x7 taps, reflect padding ----
    int cc[7];
#pragma unroll
    for (int dx = 0; dx < 7; ++dx) {
        int c0 = w + dx - 3;
        cc[dx] = c0 < 0 ? -c0 : (c0 > 255 ? 510 - c0 : c0);
    }
    float acc[8];
#pragma unroll
    for (int m = 0; m < 8; ++m) acc[m] = 0.f;
    const float* xb = xlow + (size_t)b * HW_ * MID + mh * 8;
    for (int dy = 0; dy < 7; ++dy) {
        int hy = h + dy - 3;
        hy = hy < 0 ? -hy : (hy > 255 ? 510 - hy : hy);
        float e[7];
#pragma unroll
        for (int dx = 0; dx < 7; ++dx) {
            int tp = dy * 7 + dx;
            e[dx] = fmaf(wk[0], base[tp],
                    fmaf(wk[1], base[49 + tp],
                    fmaf(wk[2], base[98 + tp], wk[3] * base[147 + tp])));
        }
        const float* rowb = xb + (size_t)hy * W_ * MID;
#pragma unroll
        for (int dx = 0; dx < 7; ++dx) {
            const float4* p = (const float4*)(rowb + cc[dx] * MID);
            float4 v0 = p[0];
            float4 v1 = p[1];
            float ed = e[dx];
            acc[0] = fmaf(ed, v0.x, acc[0]);
            acc[1] = fmaf(ed, v0.y, acc[1]);
            acc[2] = fmaf(ed, v0.z, acc[2]);
            acc[3] = fmaf(ed, v0.w, acc[3]);
            acc[4] = fmaf(ed, v1.x, acc[4]);
            acc[5] = fmaf(ed, v1.y, acc[5]);
            acc[6] = fmaf(ed, v1.z, acc[6]);
            acc[7] = fmaf(ed, v1.w, acc[7]);
        }
    }
    float4* op = (float4*)(olow + ((size_t)b * HW_ + h * W_ + w) * MID + mh * 8);
    op[0] = make_float4(acc[0], acc[1], acc[2], acc[3]);
    op[1] = make_float4(acc[4], acc[5], acc[6], acc[7]);
}

// ---------------------------------------------------------------------------
// kC: expand 16->256, streaming writes at full occupancy.
// 4096 blocks = b(2) x h(256) x cchunk(8); 256 thr = w; 32 channels/thread.
// ---------------------------------------------------------------------------
__global__ __launch_bounds__(256) void kC_expand(const float* __restrict__ olow,
                                                 const float* __restrict__ ew,
                                                 float* __restrict__ out) {
    int bid = blockIdx.x;
    int cch = bid & 7;
    int h = (bid >> 3) & 255;
    int b = bid >> 11;
    int w = threadIdx.x;
    const float4* ip = (const float4*)(olow + ((size_t)b * HW_ + h * W_ + w) * MID);
    float4 m0 = ip[0], m1 = ip[1], m2 = ip[2], m3 = ip[3];
    float* ob = out + ((size_t)b * C_ + cch * 32) * HW_ + h * W_ + w;
#pragma unroll 8
    for (int ci = 0; ci < 32; ++ci) {
        const float* wc = ew + (size_t)(cch * 32 + ci) * MID;
        float s;
        s = wc[0] * m0.x;
        s = fmaf(wc[1], m0.y, s);
        s = fmaf(wc[2], m0.z, s);
        s = fmaf(wc[3], m0.w, s);
        s = fmaf(wc[4], m1.x, s);
        s = fmaf(wc[5], m1.y, s);
        s = fmaf(wc[6], m1.z, s);
        s = fmaf(wc[7], m1.w, s);
        s = fmaf(wc[8], m2.x, s);
        s = fmaf(wc[9], m2.y, s);
        s = fmaf(wc[10], m2.z, s);
        s = fmaf(wc[11], m2.w, s);
        s = fmaf(wc[12], m3.x, s);
        s = fmaf(wc[13], m3.y, s);
        s = fmaf(wc[14], m3.z, s);
        s = fmaf(wc[15], m3.w, s);
        __builtin_nontemporal_store(s, ob + (size_t)ci * HW_);
    }
}

// ---------------------------------------------------------------------------
extern "C" void kernel_launch(void* const* d_in, const int* in_sizes, int n_in,
                              void* d_out, int out_size, void* d_ws, size_t ws_size,
                              hipStream_t stream) {
    const float* x     = (const float*)d_in[0];
    const float* angle = (const float*)d_in[1];
    const float* rw    = (const float*)d_in[2];
    const float* ew    = (const float*)d_in[3];
    const float* w1    = (const float*)d_in[4];
    const float* b1    = (const float*)d_in[5];
    const float* w2    = (const float*)d_in[6];
    const float* b2    = (const float*)d_in[7];
    float* out = (float*)d_out;

    float* wsf  = (float*)d_ws;
    float* base = wsf;                      // 196 floats
    float* rwt  = wsf + 256;                // 4096 floats (64B-aligned)
    float* xlow = wsf + 8192;               // 2*65536*16 floats, px-major
    float* olow = wsf + 8192 + B_ * HW_ * MID;  // same size, px-major

    hipLaunchKernelGGL(k0_prep,   dim3(1),    dim3(256), 0, stream, rw, base, rwt);
    hipLaunchKernelGGL(kA_reduce, dim3(512),  dim3(256), 0, stream, x, rwt, xlow);
    hipLaunchKernelGGL(kB_conv,   dim3(1024), dim3(256), 0, stream,
                       xlow, base, angle, w1, b1, w2, b2, olow);
    hipLaunchKernelGGL(kC_expand, dim3(4096), dim3(256), 0, stream, olow, ew, out);
}